// Round 7
// baseline (506.262 us; speedup 1.0000x reference)
//
#include <hip/hip_runtime.h>
#include <hip/hip_bf16.h>
#include <stdint.h>

// ---- constants for this problem ----
// B=4, S=4096, D=1024, M=4096. DECAY=0.9
#define BSZ 4
#define SEQ 4096
#define DIM 1024
#define MDIM 4096
#define DECAYF 0.9f
#define OMD 0.1f
#define CHUNK 128
#define NCHUNK 32           // SEQ / CHUNK
#define DECAY_CHUNK 1.3901844577868923e-06f  // 0.9^128

typedef __bf16 bf16_t;
typedef __bf16 bf16x8 __attribute__((ext_vector_type(8)));
typedef __bf16 bf16x4 __attribute__((ext_vector_type(4)));
typedef float floatx4 __attribute__((ext_vector_type(4)));

// ---- async global->LDS, 16B per lane. lds ptr must be wave-uniform base;
//      HW writes lane i at base + i*16 (m97 pattern). ----
__device__ __forceinline__ void load16_lds(const void* g, void* l) {
  __builtin_amdgcn_global_load_lds(
      (__attribute__((address_space(1))) void*)g,
      (__attribute__((address_space(3))) void*)l,
      16, 0, 0);
}

// R11: fragment software-pipelining (reads one phase AHEAD of use).
// R9/R10 ledger closed: K-tile = MFMA 2480cyc + LDS 750 + VALU 2030, all
// SERIAL because phase = {reads; BAR; lgkm0; MFMA; BAR} services reads only
// in the barrier window. Rotated schedule overlaps phase-N+1 reads under
// phase-N MFMA. NO manual lgkm waits: frags are plain C++ LDS loads, the
// compiler inserts exact counted lgkmcnt before each consuming MFMA (G7),
// sidestepping rule #18. sched_barrier(0) pins phase membership. 3 barriers
// per K-tile (was 9). Counted boundary vmcnt(6) only (T4).
#define SB()  __builtin_amdgcn_sched_barrier(0)
#define BAR() __builtin_amdgcn_s_barrier()

// ---------------- scan kernels (unchanged, proven) ----------------
__global__ void scan_chunk_kernel(const float* __restrict__ x,
                                  float* __restrict__ chunk_end) {
  int t = blockIdx.x * 256 + threadIdx.x;
  int d = t & (DIM - 1);
  int c = (t >> 10) & (NCHUNK - 1);
  int b = t >> 15;
  const float* xp = x + ((size_t)(b * SEQ + c * CHUNK + 64)) * DIM + d;
  float p = 0.f;
#pragma unroll 8
  for (int s = 0; s < 64; ++s) p = DECAYF * p + OMD * xp[(size_t)s * DIM];
  chunk_end[t] = p;
}

__global__ void scan_carry_kernel(const float* __restrict__ chunk_end,
                                  float* __restrict__ carry_in,
                                  float* __restrict__ final_state) {
  int t = blockIdx.x * 256 + threadIdx.x;
  int d = t & (DIM - 1);
  int b = t >> 10;
  float carry = 0.f;
#pragma unroll
  for (int c = 0; c < NCHUNK; ++c) {
    int idx = (b * NCHUNK + c) * DIM + d;
    carry_in[idx] = carry;
    carry = carry * DECAY_CHUNK + chunk_end[idx];
  }
  final_state[t] = carry;  // == current_states[b, S-1, d]
}

__global__ void scan_emit_kernel(const float* __restrict__ x,
                                 const float* __restrict__ carry_in,
                                 bf16_t* __restrict__ prev) {
  int t = blockIdx.x * 256 + threadIdx.x;
  int d = t & (DIM - 1);
  int c = (t >> 10) & (NCHUNK - 1);
  int b = t >> 15;
  size_t base = ((size_t)(b * SEQ + c * CHUNK)) * DIM + d;
  const float* xp = x + base;
  bf16_t* pp = prev + base;
  float cs = carry_in[t];  // == current_states[b, c*CHUNK - 1, d]
#pragma unroll 4
  for (int s = 0; s < CHUNK; ++s) {
    pp[(size_t)s * DIM] = (bf16_t)cs;   // prev[t] = cs[t-1]
    cs = DECAYF * cs + OMD * xp[(size_t)s * DIM];
  }
}

// ---------------- fp32 -> bf16 convert (4 elems / thread) ----------------
__global__ void cvt_bf16_kernel(const float* __restrict__ w, bf16_t* __restrict__ o) {
  int t = blockIdx.x * 256 + threadIdx.x;
  float4 v = ((const float4*)w)[t];
  bf16x4 r = { (bf16_t)v.x, (bf16_t)v.y, (bf16_t)v.z, (bf16_t)v.w };
  ((bf16x4*)o)[t] = r;
}

// ---------------- GEMM: C[M][N] = A[M][K] * B[N][K]^T  (K-contiguous bf16)
// 256x256 tile, BK=64, 512 threads (8 waves, 2Mx4N, each 128x64 of C).
// Rotated 4-phase pipeline per K-tile (frags read one phase ahead):
//   pre-loop: R_lo(0) = a0,b0
//   P1: read a1(cur); stage B1(t+1)->alt;          MFMA(a0,b0) lo-lo; BAR
//   P2: read b1(cur);                              MFMA(a1,b0) hi-lo; BAR
//   P3: stage A(t+2),B0(t+2)->cur;                 MFMA(a0,b1) lo-hi;
//       vmcnt(6); BAR   (boundary: tile t+1 fully landed, t+2 in flight)
//   P0': read a0,b0 from ALT buf (tile t+1);       MFMA(a1,b1) hi-hi
// Each phase's reads are serviced by the LDS engine DURING the same-phase
// MFMA cluster (consumers are one phase later) -> LDS BW hidden under MFMA.
//
// vmcnt ledger: stages P1:+2 (t+1).B1; P3:+4 (t+2).A, +2 (t+2).B0.
// Boundary vmcnt(6) leaves exactly (t+2).{A,B0}; retires (t+1).B1 and all
// older -> after the following BAR every wave may read any of tile t+1
// (cross-wave publication = own-vmcnt THEN barrier, for all waves).
// Overwrite licensing: B1(t+1)@P1 over alt-B-hi (readers done P2(t-1)+BAR);
// A(t+2)@P3 over cur-A (readers a0@P0'(t-1), a1@P1(t), done by P2-end BAR);
// B0(t+2)@P3 over cur-B-lo (readers b0@P0'(t-1), done by P1-end BAR).
//
// LDS: linear row-major [256][64] bf16 per operand buffer (row stride 128B)
// for global_load_lds; conflict-free swizzle col-byte bits 4-6 ^= row bits
// 1-3 as pre-swizzled GLOBAL source column + same XOR in read addresses
// (rule #21). Refcheck'd R2/R9/R10; SQ_LDS_BANK_CONFLICT == 0 measured.
#define READ_A(dst, CA, MH)                                                    \
  _Pragma("unroll") for (int i_ = 0; i_ < 4; ++i_)                             \
      _Pragma("unroll") for (int k_ = 0; k_ < 2; ++k_)                         \
          dst[i_][k_] = *(const bf16x8*)((const char*)(CA) + wrBase +          \
                                         (MH) * 8192 + i_ * 2048 + rbase +     \
                                         ((k_ * 64 + kc) ^ lswz));

#define READ_B(dst, CB, NH)                                                    \
  _Pragma("unroll") for (int j_ = 0; j_ < 2; ++j_)                             \
      _Pragma("unroll") for (int k_ = 0; k_ < 2; ++k_)                         \
          dst[j_][k_] = *(const bf16x8*)((const char*)(CB) + wcBase +          \
                                         (NH) * 4096 + j_ * 2048 + rbase +     \
                                         ((k_ * 64 + kc) ^ lswz));

#define MMQ(AF, BF, MO, NO)                                                    \
  _Pragma("unroll") for (int k_ = 0; k_ < 2; ++k_)                             \
      _Pragma("unroll") for (int i_ = 0; i_ < 4; ++i_)                         \
          _Pragma("unroll") for (int j_ = 0; j_ < 2; ++j_)                     \
              acc[(MO) + i_][(NO) + j_] =                                      \
                  __builtin_amdgcn_mfma_f32_16x16x32_bf16(                     \
                      AF[i_][k_], BF[j_][k_], acc[(MO) + i_][(NO) + j_],       \
                      0, 0, 0);

template <int N, int K, int MT, int EPI>
__global__ __launch_bounds__(512, 2) void gemm256_kernel(
    const bf16_t* __restrict__ A, const bf16_t* __restrict__ B,
    void* __restrict__ Cout, const float* __restrict__ X,
    float* __restrict__ loss_acc) {
  constexpr int NT = N / 256;
  constexpr int NTK = K / 64;
  static_assert((NTK & 1) == 0 && NTK >= 4, "even K-tile count");
  static_assert(MT % 8 == 0, "m-tiles divisible by XCD count");
  __shared__ __attribute__((aligned(16))) bf16_t sA[2][16384];  // 2 x 32KB
  __shared__ __attribute__((aligned(16))) bf16_t sB[2][16384];  // 2 x 32KB

  const int tid = threadIdx.x;
  const int wave = tid >> 6;
  const int lane = tid & 63;
  const int bid = blockIdx.x;
  const int xcd = bid & 7;
  const int slot = bid >> 3;
  const int tm = (xcd * (MT / 8) + slot / NT) * 256;
  const int tn = (slot % NT) * 256;
  const int wr = wave >> 2;                 // 0..1 : wave row (128 C-rows)
  const int wc = wave & 3;                  // 0..3 : wave col (64 C-cols)
  const int wrBase = wr * 16384;            // byte base of wave's A rows
  const int wcBase = wc * 8192;             // byte base of wave's B rows
  const int rbase = (lane & 15) * 128;
  const int kc = (lane >> 4) * 16;
  const int lswz = ((lane >> 1) & 7) << 4;
  const int srow = wave * 8 + (lane >> 3);
  const int scolb = ((lane & 7) * 16) ^ (((srow >> 1) & 7) << 4);

  floatx4 acc[8][4];
#pragma unroll
  for (int i = 0; i < 8; ++i)
#pragma unroll
    for (int j = 0; j < 4; ++j) acc[i][j] = (floatx4){0.f, 0.f, 0.f, 0.f};

  // fragment registers persist across phases/tiles (pipelined)
  bf16x8 a0[4][2], a1[4][2], b0[2][2], b1[2][2];

  // stage one half-tile (128 rows x 64 cols of one operand) = 2 DMA / thread
  auto stage_ht = [&](const bf16_t* G, int tb, bf16_t* lbuf, int kt, int h) {
    char* lbase = (char*)lbuf + h * 16384 + wave * 1024;
    const char* gbase =
        (const char*)G + ((size_t)(tb + h * 128 + srow) * K + kt) * 2 + scolb;
    load16_lds(gbase, lbase);                              // rows r+0..63
    load16_lds(gbase + (size_t)64 * K * 2, lbase + 8192);  // rows r+64..127
  };

  auto tileR = [&](int t, bf16_t* cA, bf16_t* cB, bf16_t* nA, bf16_t* nB) {
    const int kt2 = (t + 2) * 64;
    // ---- P1: read a1(cur) [used P2]; stage (t+1).B1; MFMA lo-lo
    READ_A(a1, cA, 1);
    if (t + 1 < NTK) stage_ht(B, tn, nB, (t + 1) * 64, 1);
    SB();
    __builtin_amdgcn_s_setprio(1);
    MMQ(a0, b0, 0, 0);
    __builtin_amdgcn_s_setprio(0);
    SB(); BAR();
    // ---- P2: read b1(cur) [used P3]; MFMA hi-lo
    READ_B(b1, cB, 1);
    SB();
    __builtin_amdgcn_s_setprio(1);
    MMQ(a1, b0, 4, 0);
    __builtin_amdgcn_s_setprio(0);
    SB(); BAR();
    // ---- P3: stage (t+2).{A,B0} into cur; MFMA lo-hi; boundary
    if (t + 2 < NTK) {
      stage_ht(A, tm, cA, kt2, 0);
      stage_ht(A, tm, cA, kt2, 1);
      stage_ht(B, tn, cB, kt2, 0);
    }
    SB();
    __builtin_amdgcn_s_setprio(1);
    MMQ(a0, b1, 0, 2);
    __builtin_amdgcn_s_setprio(0);
    SB();
    if (t + 2 < NTK) { asm volatile("s_waitcnt vmcnt(6)"); }
    else             { asm volatile("s_waitcnt vmcnt(0)"); }
    SB(); BAR();
    // ---- P0': read next tile's a0,b0 from alt buf [used next P1]; MFMA hi-hi
    if (t + 1 < NTK) {
      READ_A(a0, nA, 0);
      READ_B(b0, nB, 0);
    }
    SB();
    __builtin_amdgcn_s_setprio(1);
    MMQ(a1, b1, 4, 2);
    __builtin_amdgcn_s_setprio(0);
    SB();
    // no barrier here: next-phase stage targets were licensed by P1/P2-end
    // barriers of THIS tile; next-phase reads were published at the boundary.
  };

  // prologue: tile0 fully + tile1.{A,B0} (14 loads); vmcnt(6) -> tile0
  // landed, 6 loads (tile1.A,B0) in flight = steady-state precondition.
  stage_ht(A, tm, sA[0], 0, 0);
  stage_ht(A, tm, sA[0], 0, 1);
  stage_ht(B, tn, sB[0], 0, 0);
  stage_ht(B, tn, sB[0], 0, 1);
  stage_ht(A, tm, sA[1], 64, 0);
  stage_ht(A, tm, sA[1], 64, 1);
  stage_ht(B, tn, sB[1], 64, 0);
  asm volatile("s_waitcnt vmcnt(6)");
  SB(); BAR();
  READ_A(a0, sA[0], 0);   // R_lo(0): consumed by first P1's MFMA
  READ_B(b0, sB[0], 0);
  SB();

#pragma unroll 1
  for (int t = 0; t < NTK; t += 2) {
    tileR(t, sA[0], sB[0], sA[1], sB[1]);
    tileR(t + 1, sA[1], sB[1], sA[0], sB[0]);
  }

  // epilogue. C/D frag: col = lane&15, row = (lane>>4)*4 + reg
  const int r0 = (lane >> 4) * 4;
  const int cn = lane & 15;
  if constexpr (EPI == 0) {
    bf16_t* H = (bf16_t*)Cout;
#pragma unroll
    for (int i = 0; i < 8; ++i)
#pragma unroll
      for (int j = 0; j < 4; ++j)
#pragma unroll
        for (int r = 0; r < 4; ++r) {
          int m = tm + wr * 128 + i * 16 + r0 + r;
          int n = tn + wc * 64 + j * 16 + cn;
          float v = acc[i][j][r];
          v = v / (1.f + __expf(-v));  // silu
          H[(size_t)m * N + n] = (bf16_t)v;
        }
  } else {
    float* O = (float*)Cout;
    float ls = 0.f;
#pragma unroll
    for (int i = 0; i < 8; ++i)
#pragma unroll
      for (int j = 0; j < 4; ++j)
#pragma unroll
        for (int r = 0; r < 4; ++r) {
          int m = tm + wr * 128 + i * 16 + r0 + r;
          int n = tn + wc * 64 + j * 16 + cn;
          size_t off = (size_t)m * N + n;
          float v = acc[i][j][r];
          O[off] = v;
          float dd = v - X[off];
          ls += dd * dd;
        }
    // wave reduction then one atomic per wave
#pragma unroll
    for (int s = 32; s > 0; s >>= 1) ls += __shfl_down(ls, s, 64);
    if (lane == 0) atomicAdd(loss_acc, ls);
  }
}

#undef READ_A
#undef READ_B
#undef MMQ

__global__ void finalize_loss_kernel(const float* __restrict__ loss_acc,
                                     float* __restrict__ out) {
  if (threadIdx.x == 0)
    out[0] = loss_acc[0] * (1.0f / (float)(BSZ * SEQ * DIM));
}

// ---------------- launch ----------------
extern "C" void kernel_launch(void* const* d_in, const int* in_sizes, int n_in,
                              void* d_out, int out_size, void* d_ws, size_t ws_size,
                              hipStream_t stream) {
  const float* x  = (const float*)d_in[0];   // [4][4096][1024]
  const float* w1 = (const float*)d_in[1];   // [4096][1024]
  const float* w2 = (const float*)d_in[2];   // [1024][4096]
  float* out = (float*)d_out;                // mem_out | loss | final_state

  const int BT = BSZ * SEQ;                  // 16384 rows, 64 m-tiles of 256
  char* ws = (char*)d_ws;
  // workspace layout (bytes)
  bf16_t* prev      = (bf16_t*)(ws);                      // 16M bf16  = 33,554,432 B
  bf16_t* h         = (bf16_t*)(ws + 33554432ull);        // 64M bf16  = 134,217,728 B
  bf16_t* w1b       = (bf16_t*)(ws + 167772160ull);       // 4M bf16   = 8,388,608 B
  bf16_t* w2b       = (bf16_t*)(ws + 176160768ull);       // 4M bf16   = 8,388,608 B
  float*  chunk_end = (float*)(ws + 184549376ull);        // 128K f32  = 524,288 B
  float*  carry_in  = (float*)(ws + 185073664ull);        // 128K f32  = 524,288 B
  float*  loss_acc  = (float*)(ws + 185597952ull);        // 4 B

  hipMemsetAsync(loss_acc, 0, sizeof(float), stream);

  // weights -> bf16 (4,194,304 elems each; 4/thread)
  cvt_bf16_kernel<<<4096, 256, 0, stream>>>(w1, w1b);
  cvt_bf16_kernel<<<4096, 256, 0, stream>>>(w2, w2b);

  // chunked EMA scan -> prev states (bf16) + final_state (fp32, d_out tail)
  scan_chunk_kernel<<<(BSZ * NCHUNK * DIM) / 256, 256, 0, stream>>>(x, chunk_end);
  scan_carry_kernel<<<(BSZ * DIM) / 256, 256, 0, stream>>>(chunk_end, carry_in,
                                                           out + 16777217);
  scan_emit_kernel<<<(BSZ * NCHUNK * DIM) / 256, 256, 0, stream>>>(x, carry_in, prev);

  // h = silu(prev @ w1^T)  : [16384 x 1024] x [4096 x 1024]^T -> bf16 [16384 x 4096]
  gemm256_kernel<MDIM, DIM, BT / 256, 0>
      <<<(BT / 256) * (MDIM / 256), 512, 0, stream>>>(prev, w1b, h, nullptr, nullptr);

  // mem_out = h @ w2^T : [16384 x 4096] x [1024 x 4096]^T -> fp32 [16384 x 1024]
  // fused: loss partial sums vs x
  gemm256_kernel<DIM, MDIM, BT / 256, 1>
      <<<(BT / 256) * (DIM / 256), 512, 0, stream>>>(h, w2b, out, x, loss_acc);

  finalize_loss_kernel<<<1, 64, 0, stream>>>(loss_acc, out + 16777216);
}

// Round 8
// 483.135 us; speedup vs baseline: 1.0479x; 1.0479x over previous
//
#include <hip/hip_runtime.h>
#include <hip/hip_bf16.h>
#include <stdint.h>

// ---- constants for this problem ----
// B=4, S=4096, D=1024, M=4096. DECAY=0.9
#define BSZ 4
#define SEQ 4096
#define DIM 1024
#define MDIM 4096
#define DECAYF 0.9f
#define OMD 0.1f
#define CHUNK 128
#define NCHUNK 32           // SEQ / CHUNK
#define DECAY_CHUNK 1.3901844577868923e-06f  // 0.9^128

typedef __bf16 bf16_t;
typedef __bf16 bf16x8 __attribute__((ext_vector_type(8)));
typedef __bf16 bf16x4 __attribute__((ext_vector_type(4)));
typedef float floatx4 __attribute__((ext_vector_type(4)));

// ---- async global->LDS, 16B per lane. lds ptr must be wave-uniform base;
//      HW writes lane i at base + i*16 (m97 pattern). ----
__device__ __forceinline__ void load16_lds(const void* g, void* l) {
  __builtin_amdgcn_global_load_lds(
      (__attribute__((address_space(1))) void*)g,
      (__attribute__((address_space(3))) void*)l,
      16, 0, 0);
}

// R12 = R11 pipeline + __launch_bounds__(512, 1).
// R11 regressed via REGISTER SPILLS: launch_bounds(512,2) capped VGPR at 128
// while the rotated pipeline needs ~240 live (frags 96 + acc 128 + addr);
// signature = WRITE_SIZE +30MB / FETCH +8MB scratch traffic, and scratch
// vmem ops polluting the counted vmcnt ledger. The (512,2) bound was void
// anyway: 128KB LDS/block on a 160KB CU -> 1 block/CU resident, period.
// At 1 block/CU each wave gets 256 VGPR -> pipeline fits, spills gone.
//
// Schedule (unchanged from R11): rotated 4-phase, frag reads one phase ahead
// of their consuming MFMA so the LDS engine services them UNDER the MFMA
// cluster; no manual lgkm waits (compiler emits exact counted lgkmcnt, G7);
// 3 barriers/K-tile; counted boundary vmcnt(6) only (T4); setprio (T5).
#define SB()  __builtin_amdgcn_sched_barrier(0)
#define BAR() __builtin_amdgcn_s_barrier()

// ---------------- scan kernels (unchanged, proven) ----------------
__global__ void scan_chunk_kernel(const float* __restrict__ x,
                                  float* __restrict__ chunk_end) {
  int t = blockIdx.x * 256 + threadIdx.x;
  int d = t & (DIM - 1);
  int c = (t >> 10) & (NCHUNK - 1);
  int b = t >> 15;
  const float* xp = x + ((size_t)(b * SEQ + c * CHUNK + 64)) * DIM + d;
  float p = 0.f;
#pragma unroll 8
  for (int s = 0; s < 64; ++s) p = DECAYF * p + OMD * xp[(size_t)s * DIM];
  chunk_end[t] = p;
}

__global__ void scan_carry_kernel(const float* __restrict__ chunk_end,
                                  float* __restrict__ carry_in,
                                  float* __restrict__ final_state) {
  int t = blockIdx.x * 256 + threadIdx.x;
  int d = t & (DIM - 1);
  int b = t >> 10;
  float carry = 0.f;
#pragma unroll
  for (int c = 0; c < NCHUNK; ++c) {
    int idx = (b * NCHUNK + c) * DIM + d;
    carry_in[idx] = carry;
    carry = carry * DECAY_CHUNK + chunk_end[idx];
  }
  final_state[t] = carry;  // == current_states[b, S-1, d]
}

__global__ void scan_emit_kernel(const float* __restrict__ x,
                                 const float* __restrict__ carry_in,
                                 bf16_t* __restrict__ prev) {
  int t = blockIdx.x * 256 + threadIdx.x;
  int d = t & (DIM - 1);
  int c = (t >> 10) & (NCHUNK - 1);
  int b = t >> 15;
  size_t base = ((size_t)(b * SEQ + c * CHUNK)) * DIM + d;
  const float* xp = x + base;
  bf16_t* pp = prev + base;
  float cs = carry_in[t];  // == current_states[b, c*CHUNK - 1, d]
#pragma unroll 4
  for (int s = 0; s < CHUNK; ++s) {
    pp[(size_t)s * DIM] = (bf16_t)cs;   // prev[t] = cs[t-1]
    cs = DECAYF * cs + OMD * xp[(size_t)s * DIM];
  }
}

// ---------------- fp32 -> bf16 convert (4 elems / thread) ----------------
__global__ void cvt_bf16_kernel(const float* __restrict__ w, bf16_t* __restrict__ o) {
  int t = blockIdx.x * 256 + threadIdx.x;
  float4 v = ((const float4*)w)[t];
  bf16x4 r = { (bf16_t)v.x, (bf16_t)v.y, (bf16_t)v.z, (bf16_t)v.w };
  ((bf16x4*)o)[t] = r;
}

// ---------------- GEMM: C[M][N] = A[M][K] * B[N][K]^T  (K-contiguous bf16)
// 256x256 tile, BK=64, 512 threads (8 waves, 2Mx4N, each 128x64 of C).
// Rotated 4-phase pipeline per K-tile (frags read one phase ahead):
//   pre-loop: R_lo(0) = a0,b0
//   P1: read a1(cur); stage B1(t+1)->alt;          MFMA(a0,b0) lo-lo; BAR
//   P2: read b1(cur);                              MFMA(a1,b0) hi-lo; BAR
//   P3: stage A(t+2),B0(t+2)->cur;                 MFMA(a0,b1) lo-hi;
//       vmcnt(6); BAR   (boundary: tile t+1 fully landed, t+2 in flight)
//   P0': read a0,b0 from ALT buf (tile t+1);       MFMA(a1,b1) hi-hi
//
// vmcnt ledger: stages P1:+2 (t+1).B1; P3:+4 (t+2).A, +2 (t+2).B0.
// Boundary vmcnt(6) leaves exactly (t+2).{A,B0}; retires (t+1).B1 and all
// older -> after the following BAR every wave may read any of tile t+1.
// Overwrite licensing: B1(t+1)@P1 over alt-B-hi (readers done P2(t-1)+BAR);
// A(t+2)@P3 over cur-A (readers a0@P0'(t-1), a1@P1(t), done by P2-end BAR);
// B0(t+2)@P3 over cur-B-lo (readers b0@P0'(t-1), done by P1-end BAR).
//
// LDS: linear row-major [256][64] bf16 per operand buffer (row stride 128B)
// for global_load_lds; conflict-free swizzle col-byte bits 4-6 ^= row bits
// 1-3 as pre-swizzled GLOBAL source column + same XOR in read addresses
// (rule #21). Refcheck'd R2/R9/R10/R11; SQ_LDS_BANK_CONFLICT == 0 measured.
#define READ_A(dst, CA, MH)                                                    \
  _Pragma("unroll") for (int i_ = 0; i_ < 4; ++i_)                             \
      _Pragma("unroll") for (int k_ = 0; k_ < 2; ++k_)                         \
          dst[i_][k_] = *(const bf16x8*)((const char*)(CA) + wrBase +          \
                                         (MH) * 8192 + i_ * 2048 + rbase +     \
                                         ((k_ * 64 + kc) ^ lswz));

#define READ_B(dst, CB, NH)                                                    \
  _Pragma("unroll") for (int j_ = 0; j_ < 2; ++j_)                             \
      _Pragma("unroll") for (int k_ = 0; k_ < 2; ++k_)                         \
          dst[j_][k_] = *(const bf16x8*)((const char*)(CB) + wcBase +          \
                                         (NH) * 4096 + j_ * 2048 + rbase +     \
                                         ((k_ * 64 + kc) ^ lswz));

#define MMQ(AF, BF, MO, NO)                                                    \
  _Pragma("unroll") for (int k_ = 0; k_ < 2; ++k_)                             \
      _Pragma("unroll") for (int i_ = 0; i_ < 4; ++i_)                         \
          _Pragma("unroll") for (int j_ = 0; j_ < 2; ++j_)                     \
              acc[(MO) + i_][(NO) + j_] =                                      \
                  __builtin_amdgcn_mfma_f32_16x16x32_bf16(                     \
                      AF[i_][k_], BF[j_][k_], acc[(MO) + i_][(NO) + j_],       \
                      0, 0, 0);

template <int N, int K, int MT, int EPI>
__global__ __launch_bounds__(512, 1) void gemm256_kernel(
    const bf16_t* __restrict__ A, const bf16_t* __restrict__ B,
    void* __restrict__ Cout, const float* __restrict__ X,
    float* __restrict__ loss_acc) {
  constexpr int NT = N / 256;
  constexpr int NTK = K / 64;
  static_assert((NTK & 1) == 0 && NTK >= 4, "even K-tile count");
  static_assert(MT % 8 == 0, "m-tiles divisible by XCD count");
  __shared__ __attribute__((aligned(16))) bf16_t sA[2][16384];  // 2 x 32KB
  __shared__ __attribute__((aligned(16))) bf16_t sB[2][16384];  // 2 x 32KB

  const int tid = threadIdx.x;
  const int wave = tid >> 6;
  const int lane = tid & 63;
  const int bid = blockIdx.x;
  const int xcd = bid & 7;
  const int slot = bid >> 3;
  const int tm = (xcd * (MT / 8) + slot / NT) * 256;
  const int tn = (slot % NT) * 256;
  const int wr = wave >> 2;                 // 0..1 : wave row (128 C-rows)
  const int wc = wave & 3;                  // 0..3 : wave col (64 C-cols)
  const int wrBase = wr * 16384;            // byte base of wave's A rows
  const int wcBase = wc * 8192;             // byte base of wave's B rows
  const int rbase = (lane & 15) * 128;
  const int kc = (lane >> 4) * 16;
  const int lswz = ((lane >> 1) & 7) << 4;
  const int srow = wave * 8 + (lane >> 3);
  const int scolb = ((lane & 7) * 16) ^ (((srow >> 1) & 7) << 4);

  floatx4 acc[8][4];
#pragma unroll
  for (int i = 0; i < 8; ++i)
#pragma unroll
    for (int j = 0; j < 4; ++j) acc[i][j] = (floatx4){0.f, 0.f, 0.f, 0.f};

  // fragment registers persist across phases/tiles (pipelined)
  bf16x8 a0[4][2], a1[4][2], b0[2][2], b1[2][2];

  // stage one half-tile (128 rows x 64 cols of one operand) = 2 DMA / thread
  auto stage_ht = [&](const bf16_t* G, int tb, bf16_t* lbuf, int kt, int h) {
    char* lbase = (char*)lbuf + h * 16384 + wave * 1024;
    const char* gbase =
        (const char*)G + ((size_t)(tb + h * 128 + srow) * K + kt) * 2 + scolb;
    load16_lds(gbase, lbase);                              // rows r+0..63
    load16_lds(gbase + (size_t)64 * K * 2, lbase + 8192);  // rows r+64..127
  };

  auto tileR = [&](int t, bf16_t* cA, bf16_t* cB, bf16_t* nA, bf16_t* nB) {
    const int kt2 = (t + 2) * 64;
    // ---- P1: read a1(cur) [used P2]; stage (t+1).B1; MFMA lo-lo
    READ_A(a1, cA, 1);
    if (t + 1 < NTK) stage_ht(B, tn, nB, (t + 1) * 64, 1);
    SB();
    __builtin_amdgcn_s_setprio(1);
    MMQ(a0, b0, 0, 0);
    __builtin_amdgcn_s_setprio(0);
    SB(); BAR();
    // ---- P2: read b1(cur) [used P3]; MFMA hi-lo
    READ_B(b1, cB, 1);
    SB();
    __builtin_amdgcn_s_setprio(1);
    MMQ(a1, b0, 4, 0);
    __builtin_amdgcn_s_setprio(0);
    SB(); BAR();
    // ---- P3: stage (t+2).{A,B0} into cur; MFMA lo-hi; boundary
    if (t + 2 < NTK) {
      stage_ht(A, tm, cA, kt2, 0);
      stage_ht(A, tm, cA, kt2, 1);
      stage_ht(B, tn, cB, kt2, 0);
    }
    SB();
    __builtin_amdgcn_s_setprio(1);
    MMQ(a0, b1, 0, 2);
    __builtin_amdgcn_s_setprio(0);
    SB();
    if (t + 2 < NTK) { asm volatile("s_waitcnt vmcnt(6)"); }
    else             { asm volatile("s_waitcnt vmcnt(0)"); }
    SB(); BAR();
    // ---- P0': read next tile's a0,b0 from alt buf [used next P1]; MFMA hi-hi
    if (t + 1 < NTK) {
      READ_A(a0, nA, 0);
      READ_B(b0, nB, 0);
    }
    SB();
    __builtin_amdgcn_s_setprio(1);
    MMQ(a1, b1, 4, 2);
    __builtin_amdgcn_s_setprio(0);
    SB();
    // no barrier here: next-phase stage targets were licensed by P1/P2-end
    // barriers of THIS tile; next-phase reads were published at the boundary.
  };

  // prologue: tile0 fully + tile1.{A,B0} (14 loads); vmcnt(6) -> tile0
  // landed, 6 loads (tile1.A,B0) in flight = steady-state precondition.
  stage_ht(A, tm, sA[0], 0, 0);
  stage_ht(A, tm, sA[0], 0, 1);
  stage_ht(B, tn, sB[0], 0, 0);
  stage_ht(B, tn, sB[0], 0, 1);
  stage_ht(A, tm, sA[1], 64, 0);
  stage_ht(A, tm, sA[1], 64, 1);
  stage_ht(B, tn, sB[1], 64, 0);
  asm volatile("s_waitcnt vmcnt(6)");
  SB(); BAR();
  READ_A(a0, sA[0], 0);   // R_lo(0): consumed by first P1's MFMA
  READ_B(b0, sB[0], 0);
  SB();

#pragma unroll 1
  for (int t = 0; t < NTK; t += 2) {
    tileR(t, sA[0], sB[0], sA[1], sB[1]);
    tileR(t + 1, sA[1], sB[1], sA[0], sB[0]);
  }

  // epilogue. C/D frag: col = lane&15, row = (lane>>4)*4 + reg
  const int r0 = (lane >> 4) * 4;
  const int cn = lane & 15;
  if constexpr (EPI == 0) {
    bf16_t* H = (bf16_t*)Cout;
#pragma unroll
    for (int i = 0; i < 8; ++i)
#pragma unroll
      for (int j = 0; j < 4; ++j)
#pragma unroll
        for (int r = 0; r < 4; ++r) {
          int m = tm + wr * 128 + i * 16 + r0 + r;
          int n = tn + wc * 64 + j * 16 + cn;
          float v = acc[i][j][r];
          v = v / (1.f + __expf(-v));  // silu
          H[(size_t)m * N + n] = (bf16_t)v;
        }
  } else {
    float* O = (float*)Cout;
    float ls = 0.f;
#pragma unroll
    for (int i = 0; i < 8; ++i)
#pragma unroll
      for (int j = 0; j < 4; ++j)
#pragma unroll
        for (int r = 0; r < 4; ++r) {
          int m = tm + wr * 128 + i * 16 + r0 + r;
          int n = tn + wc * 64 + j * 16 + cn;
          size_t off = (size_t)m * N + n;
          float v = acc[i][j][r];
          O[off] = v;
          float dd = v - X[off];
          ls += dd * dd;
        }
    // wave reduction then one atomic per wave
#pragma unroll
    for (int s = 32; s > 0; s >>= 1) ls += __shfl_down(ls, s, 64);
    if (lane == 0) atomicAdd(loss_acc, ls);
  }
}

#undef READ_A
#undef READ_B
#undef MMQ

__global__ void finalize_loss_kernel(const float* __restrict__ loss_acc,
                                     float* __restrict__ out) {
  if (threadIdx.x == 0)
    out[0] = loss_acc[0] * (1.0f / (float)(BSZ * SEQ * DIM));
}

// ---------------- launch ----------------
extern "C" void kernel_launch(void* const* d_in, const int* in_sizes, int n_in,
                              void* d_out, int out_size, void* d_ws, size_t ws_size,
                              hipStream_t stream) {
  const float* x  = (const float*)d_in[0];   // [4][4096][1024]
  const float* w1 = (const float*)d_in[1];   // [4096][1024]
  const float* w2 = (const float*)d_in[2];   // [1024][4096]
  float* out = (float*)d_out;                // mem_out | loss | final_state

  const int BT = BSZ * SEQ;                  // 16384 rows, 64 m-tiles of 256
  char* ws = (char*)d_ws;
  // workspace layout (bytes)
  bf16_t* prev      = (bf16_t*)(ws);                      // 16M bf16  = 33,554,432 B
  bf16_t* h         = (bf16_t*)(ws + 33554432ull);        // 64M bf16  = 134,217,728 B
  bf16_t* w1b       = (bf16_t*)(ws + 167772160ull);       // 4M bf16   = 8,388,608 B
  bf16_t* w2b       = (bf16_t*)(ws + 176160768ull);       // 4M bf16   = 8,388,608 B
  float*  chunk_end = (float*)(ws + 184549376ull);        // 128K f32  = 524,288 B
  float*  carry_in  = (float*)(ws + 185073664ull);        // 128K f32  = 524,288 B
  float*  loss_acc  = (float*)(ws + 185597952ull);        // 4 B

  hipMemsetAsync(loss_acc, 0, sizeof(float), stream);

  // weights -> bf16 (4,194,304 elems each; 4/thread)
  cvt_bf16_kernel<<<4096, 256, 0, stream>>>(w1, w1b);
  cvt_bf16_kernel<<<4096, 256, 0, stream>>>(w2, w2b);

  // chunked EMA scan -> prev states (bf16) + final_state (fp32, d_out tail)
  scan_chunk_kernel<<<(BSZ * NCHUNK * DIM) / 256, 256, 0, stream>>>(x, chunk_end);
  scan_carry_kernel<<<(BSZ * DIM) / 256, 256, 0, stream>>>(chunk_end, carry_in,
                                                           out + 16777217);
  scan_emit_kernel<<<(BSZ * NCHUNK * DIM) / 256, 256, 0, stream>>>(x, carry_in, prev);

  // h = silu(prev @ w1^T)  : [16384 x 1024] x [4096 x 1024]^T -> bf16 [16384 x 4096]
  gemm256_kernel<MDIM, DIM, BT / 256, 0>
      <<<(BT / 256) * (MDIM / 256), 512, 0, stream>>>(prev, w1b, h, nullptr, nullptr);

  // mem_out = h @ w2^T : [16384 x 4096] x [1024 x 4096]^T -> fp32 [16384 x 1024]
  // fused: loss partial sums vs x
  gemm256_kernel<DIM, MDIM, BT / 256, 1>
      <<<(BT / 256) * (DIM / 256), 512, 0, stream>>>(h, w2b, out, x, loss_acc);

  finalize_loss_kernel<<<1, 64, 0, stream>>>(loss_acc, out + 16777216);
}

// Round 9
// 447.572 us; speedup vs baseline: 1.1311x; 1.0795x over previous
//
#include <hip/hip_runtime.h>
#include <hip/hip_bf16.h>
#include <stdint.h>

// ---- constants for this problem ----
// B=4, S=4096, D=1024, M=4096. DECAY=0.9
#define BSZ 4
#define SEQ 4096
#define DIM 1024
#define MDIM 4096
#define DECAYF 0.9f
#define OMD 0.1f
#define CHUNK 128
#define NCHUNK 32           // SEQ / CHUNK
#define DECAY_CHUNK 1.3901844577868923e-06f  // 0.9^128

typedef __bf16 bf16_t;
typedef __bf16 bf16x8 __attribute__((ext_vector_type(8)));
typedef __bf16 bf16x4 __attribute__((ext_vector_type(4)));
typedef float floatx4 __attribute__((ext_vector_type(4)));

// ---- async global->LDS, 16B per lane. lds ptr must be wave-uniform base;
//      HW writes lane i at base + i*16 (m97 pattern). ----
__device__ __forceinline__ void load16_lds(const void* g, void* l) {
  __builtin_amdgcn_global_load_lds(
      (__attribute__((address_space(1))) void*)g,
      (__attribute__((address_space(3))) void*)l,
      16, 0, 0);
}

// R13: register-budgeted read-ahead.
// Arch-VGPR budget is HARD-capped at 128: acc[8][4] pins 128 AGPRs of the
// 256/wave unified file (2 waves/SIMD, 1 block/CU by 128KB LDS). R11/R12
// kept 96 frag regs live -> ~135 arch -> spills (WRITE_SIZE +30MB scratch).
// Fix: quadrant rotation lo-lo -> lo-hi -> hi-hi -> hi-lo changes ONE
// operand per step; prefetch only that operand => peak live 80 frag regs.
// b0 re-read at P3 (+4 reads, hidden under MFMA). Stages placed AFTER the
// MFMA cluster of the phase whose reads last touched the target region
// (own-lgkm drained before license barrier = m201 safety pattern).
// One counted vmcnt(4) per K-tile (T4); no mid-loop drains; setprio (T5);
// compiler-counted lgkmcnt for all frag reads (G7); SB pins phases.
#define SB()  __builtin_amdgcn_sched_barrier(0)
#define BAR() __builtin_amdgcn_s_barrier()

// ---------------- scan kernels (unchanged, proven) ----------------
__global__ void scan_chunk_kernel(const float* __restrict__ x,
                                  float* __restrict__ chunk_end) {
  int t = blockIdx.x * 256 + threadIdx.x;
  int d = t & (DIM - 1);
  int c = (t >> 10) & (NCHUNK - 1);
  int b = t >> 15;
  const float* xp = x + ((size_t)(b * SEQ + c * CHUNK + 64)) * DIM + d;
  float p = 0.f;
#pragma unroll 8
  for (int s = 0; s < 64; ++s) p = DECAYF * p + OMD * xp[(size_t)s * DIM];
  chunk_end[t] = p;
}

__global__ void scan_carry_kernel(const float* __restrict__ chunk_end,
                                  float* __restrict__ carry_in,
                                  float* __restrict__ final_state) {
  int t = blockIdx.x * 256 + threadIdx.x;
  int d = t & (DIM - 1);
  int b = t >> 10;
  float carry = 0.f;
#pragma unroll
  for (int c = 0; c < NCHUNK; ++c) {
    int idx = (b * NCHUNK + c) * DIM + d;
    carry_in[idx] = carry;
    carry = carry * DECAY_CHUNK + chunk_end[idx];
  }
  final_state[t] = carry;  // == current_states[b, S-1, d]
}

__global__ void scan_emit_kernel(const float* __restrict__ x,
                                 const float* __restrict__ carry_in,
                                 bf16_t* __restrict__ prev) {
  int t = blockIdx.x * 256 + threadIdx.x;
  int d = t & (DIM - 1);
  int c = (t >> 10) & (NCHUNK - 1);
  int b = t >> 15;
  size_t base = ((size_t)(b * SEQ + c * CHUNK)) * DIM + d;
  const float* xp = x + base;
  bf16_t* pp = prev + base;
  float cs = carry_in[t];  // == current_states[b, c*CHUNK - 1, d]
#pragma unroll 4
  for (int s = 0; s < CHUNK; ++s) {
    pp[(size_t)s * DIM] = (bf16_t)cs;   // prev[t] = cs[t-1]
    cs = DECAYF * cs + OMD * xp[(size_t)s * DIM];
  }
}

// ---------------- fp32 -> bf16 convert (4 elems / thread) ----------------
__global__ void cvt_bf16_kernel(const float* __restrict__ w, bf16_t* __restrict__ o) {
  int t = blockIdx.x * 256 + threadIdx.x;
  float4 v = ((const float4*)w)[t];
  bf16x4 r = { (bf16_t)v.x, (bf16_t)v.y, (bf16_t)v.z, (bf16_t)v.w };
  ((bf16x4*)o)[t] = r;
}

// ---------------- GEMM: C[M][N] = A[M][K] * B[N][K]^T  (K-contiguous bf16)
// 256x256 tile, BK=64, 512 threads (8 waves, 2Mx4N, each 128x64 of C).
// Per K-tile t (cur buf c, alt buf n):
//  P1: read b0(c) in-phase + prefetch b1(c);  MFMA lo-lo(a0,b0);        BAR
//  P2: prefetch a1(c);                        MFMA lo-hi(a0,b1);        BAR
//  P3: prefetch b0re(c);                      MFMA hi-hi(a1,b1);
//      stage (t+2).A -> c;  vmcnt(4|0);                                 BAR
//  P4: prefetch a0'(n, tile t+1);             MFMA hi-lo(a1,b0re);
//      stage (t+2).B -> c;                                              BAR
//
// vmcnt ledger (issue order: P3(t):A(t+2), P4(t):B(t+2)):
//  at P3(t)'s wait, outstanding = (t+1).A(4)+(t+1).B(4)+(t+2).A(4)=12;
//  vmcnt(4) retires ALL of tile t+1, leaves (t+2).A.  Reads vs retirement:
//  b0,b1(t)@P1 retired P3(t-1); a1(t)@P2 retired P3(t-1); a0'(t+1)@P4
//  retired at P3(t) ✓ published by BAR3(t).  Tail (t+2>=NTK): vmcnt(0).
// Overwrite licensing: every stage follows the MFMA consuming the region's
// last reads (own lgkm drained) + crosses >=1 barrier + ~900cyc DMA latency
// >> max LDS queue backlog -> no read/write race.
//
// LDS: linear row-major [256][64] bf16 per operand buffer (row stride 128B)
// for global_load_lds; conflict-free swizzle col-byte bits 4-6 ^= row bits
// 1-3 as pre-swizzled GLOBAL source column + same XOR in read addresses
// (rule #21). Refcheck'd R2/R9/R10/R11/R12; SQ_LDS_BANK_CONFLICT == 0.
#define READ_A(dst, CA, MH)                                                    \
  _Pragma("unroll") for (int i_ = 0; i_ < 4; ++i_)                             \
      _Pragma("unroll") for (int k_ = 0; k_ < 2; ++k_)                         \
          dst[i_][k_] = *(const bf16x8*)((const char*)(CA) + wrBase +          \
                                         (MH) * 8192 + i_ * 2048 + rbase +     \
                                         ((k_ * 64 + kc) ^ lswz));

#define READ_B(dst, CB, NH)                                                    \
  _Pragma("unroll") for (int j_ = 0; j_ < 2; ++j_)                             \
      _Pragma("unroll") for (int k_ = 0; k_ < 2; ++k_)                         \
          dst[j_][k_] = *(const bf16x8*)((const char*)(CB) + wcBase +          \
                                         (NH) * 4096 + j_ * 2048 + rbase +     \
                                         ((k_ * 64 + kc) ^ lswz));

#define MMQ(AF, BF, MO, NO)                                                    \
  _Pragma("unroll") for (int k_ = 0; k_ < 2; ++k_)                             \
      _Pragma("unroll") for (int i_ = 0; i_ < 4; ++i_)                         \
          _Pragma("unroll") for (int j_ = 0; j_ < 2; ++j_)                     \
              acc[(MO) + i_][(NO) + j_] =                                      \
                  __builtin_amdgcn_mfma_f32_16x16x32_bf16(                     \
                      AF[i_][k_], BF[j_][k_], acc[(MO) + i_][(NO) + j_],       \
                      0, 0, 0);

template <int N, int K, int MT, int EPI>
__global__ __launch_bounds__(512, 1) void gemm256_kernel(
    const bf16_t* __restrict__ A, const bf16_t* __restrict__ B,
    void* __restrict__ Cout, const float* __restrict__ X,
    float* __restrict__ loss_acc) {
  constexpr int NT = N / 256;
  constexpr int NTK = K / 64;
  static_assert((NTK & 1) == 0 && NTK >= 4, "even K-tile count");
  static_assert(MT % 8 == 0, "m-tiles divisible by XCD count");
  __shared__ __attribute__((aligned(16))) bf16_t sA[2][16384];  // 2 x 32KB
  __shared__ __attribute__((aligned(16))) bf16_t sB[2][16384];  // 2 x 32KB

  const int tid = threadIdx.x;
  const int wave = tid >> 6;
  const int lane = tid & 63;
  const int bid = blockIdx.x;
  const int xcd = bid & 7;
  const int slot = bid >> 3;
  const int tm = (xcd * (MT / 8) + slot / NT) * 256;
  const int tn = (slot % NT) * 256;
  const int wr = wave >> 2;                 // 0..1 : wave row (128 C-rows)
  const int wc = wave & 3;                  // 0..3 : wave col (64 C-cols)
  const int wrBase = wr * 16384;            // byte base of wave's A rows
  const int wcBase = wc * 8192;             // byte base of wave's B rows
  const int rbase = (lane & 15) * 128;
  const int kc = (lane >> 4) * 16;
  const int lswz = ((lane >> 1) & 7) << 4;
  const int srow = wave * 8 + (lane >> 3);
  const int scolb = ((lane & 7) * 16) ^ (((srow >> 1) & 7) << 4);

  floatx4 acc[8][4];
#pragma unroll
  for (int i = 0; i < 8; ++i)
#pragma unroll
    for (int j = 0; j < 4; ++j) acc[i][j] = (floatx4){0.f, 0.f, 0.f, 0.f};

  // fragment registers; peak live = a0(32)+b0(16)+a1-or-b1(32/16) <= 80
  bf16x8 a0[4][2], a1[4][2], b0[2][2], b1[2][2];

  // stage one half-tile (128 rows x 64 cols of one operand) = 2 DMA / thread
  auto stage_ht = [&](const bf16_t* G, int tb, bf16_t* lbuf, int kt, int h) {
    char* lbase = (char*)lbuf + h * 16384 + wave * 1024;
    const char* gbase =
        (const char*)G + ((size_t)(tb + h * 128 + srow) * K + kt) * 2 + scolb;
    load16_lds(gbase, lbase);                              // rows r+0..63
    load16_lds(gbase + (size_t)64 * K * 2, lbase + 8192);  // rows r+64..127
  };

  auto tileQ = [&](int t, bf16_t* cA, bf16_t* cB, bf16_t* nA, bf16_t* nB) {
    const int kt2 = (t + 2) * 64;
    // ---- P1: lo-lo. b0 in-phase (compiler waits only its 4 reads), b1 ahead.
    READ_B(b0, cB, 0);
    READ_B(b1, cB, 1);
    SB();
    __builtin_amdgcn_s_setprio(1);
    MMQ(a0, b0, 0, 0);
    __builtin_amdgcn_s_setprio(0);
    SB(); BAR();
    // ---- P2: lo-hi. prefetch a1 under MFMA.
    READ_A(a1, cA, 1);
    SB();
    __builtin_amdgcn_s_setprio(1);
    MMQ(a0, b1, 0, 2);
    __builtin_amdgcn_s_setprio(0);
    SB(); BAR();
    // ---- P3: hi-hi. prefetch b0 re-read (for P4) under MFMA; then stage
    //      (t+2).A over cur-A (a1 readers drained by this wave's MFMA wait).
    READ_B(b0, cB, 0);
    SB();
    __builtin_amdgcn_s_setprio(1);
    MMQ(a1, b1, 4, 2);
    __builtin_amdgcn_s_setprio(0);
    SB();
    if (t + 2 < NTK) {
      stage_ht(A, tm, cA, kt2, 0);
      stage_ht(A, tm, cA, kt2, 1);
      asm volatile("s_waitcnt vmcnt(4)");   // retires ALL of tile t+1
    } else {
      asm volatile("s_waitcnt vmcnt(0)");   // tail: drain everything
    }
    SB(); BAR();
    // ---- P4: hi-lo. prefetch next tile's a0 from alt buf (retired+published
    //      at this tile's P3); then stage (t+2).B over cur-B.
    if (t + 1 < NTK) READ_A(a0, nA, 0);
    SB();
    __builtin_amdgcn_s_setprio(1);
    MMQ(a1, b0, 4, 0);
    __builtin_amdgcn_s_setprio(0);
    SB();
    if (t + 2 < NTK) {
      stage_ht(B, tn, cB, kt2, 0);
      stage_ht(B, tn, cB, kt2, 1);
    }
    SB(); BAR();
  };

  // prologue: stage tiles 0 and 1 fully (16 loads); vmcnt(8) -> tile 0
  // landed, tile 1 (8 loads) in flight = steady-state precondition
  // (invariant entering tile t: (t+1).{A,B} outstanding, (t).* retired).
  stage_ht(A, tm, sA[0], 0, 0);
  stage_ht(A, tm, sA[0], 0, 1);
  stage_ht(B, tn, sB[0], 0, 0);
  stage_ht(B, tn, sB[0], 0, 1);
  stage_ht(A, tm, sA[1], 64, 0);
  stage_ht(A, tm, sA[1], 64, 1);
  stage_ht(B, tn, sB[1], 64, 0);
  stage_ht(B, tn, sB[1], 64, 1);
  asm volatile("s_waitcnt vmcnt(8)");
  SB(); BAR();
  READ_A(a0, sA[0], 0);   // consumed by first P1/P2
  SB();

#pragma unroll 1
  for (int t = 0; t < NTK; t += 2) {
    tileQ(t, sA[0], sB[0], sA[1], sB[1]);
    tileQ(t + 1, sA[1], sB[1], sA[0], sB[0]);
  }

  // epilogue. C/D frag: col = lane&15, row = (lane>>4)*4 + reg
  const int r0 = (lane >> 4) * 4;
  const int cn = lane & 15;
  if constexpr (EPI == 0) {
    bf16_t* H = (bf16_t*)Cout;
#pragma unroll
    for (int i = 0; i < 8; ++i)
#pragma unroll
      for (int j = 0; j < 4; ++j)
#pragma unroll
        for (int r = 0; r < 4; ++r) {
          int m = tm + wr * 128 + i * 16 + r0 + r;
          int n = tn + wc * 64 + j * 16 + cn;
          float v = acc[i][j][r];
          v = v / (1.f + __expf(-v));  // silu
          H[(size_t)m * N + n] = (bf16_t)v;
        }
  } else {
    float* O = (float*)Cout;
    float ls = 0.f;
#pragma unroll
    for (int i = 0; i < 8; ++i)
#pragma unroll
      for (int j = 0; j < 4; ++j)
#pragma unroll
        for (int r = 0; r < 4; ++r) {
          int m = tm + wr * 128 + i * 16 + r0 + r;
          int n = tn + wc * 64 + j * 16 + cn;
          size_t off = (size_t)m * N + n;
          float v = acc[i][j][r];
          O[off] = v;
          float dd = v - X[off];
          ls += dd * dd;
        }
    // wave reduction then one atomic per wave
#pragma unroll
    for (int s = 32; s > 0; s >>= 1) ls += __shfl_down(ls, s, 64);
    if (lane == 0) atomicAdd(loss_acc, ls);
  }
}

#undef READ_A
#undef READ_B
#undef MMQ

__global__ void finalize_loss_kernel(const float* __restrict__ loss_acc,
                                     float* __restrict__ out) {
  if (threadIdx.x == 0)
    out[0] = loss_acc[0] * (1.0f / (float)(BSZ * SEQ * DIM));
}

// ---------------- launch ----------------
extern "C" void kernel_launch(void* const* d_in, const int* in_sizes, int n_in,
                              void* d_out, int out_size, void* d_ws, size_t ws_size,
                              hipStream_t stream) {
  const float* x  = (const float*)d_in[0];   // [4][4096][1024]
  const float* w1 = (const float*)d_in[1];   // [4096][1024]
  const float* w2 = (const float*)d_in[2];   // [1024][4096]
  float* out = (float*)d_out;                // mem_out | loss | final_state

  const int BT = BSZ * SEQ;                  // 16384 rows, 64 m-tiles of 256
  char* ws = (char*)d_ws;
  // workspace layout (bytes)
  bf16_t* prev      = (bf16_t*)(ws);                      // 16M bf16  = 33,554,432 B
  bf16_t* h         = (bf16_t*)(ws + 33554432ull);        // 64M bf16  = 134,217,728 B
  bf16_t* w1b       = (bf16_t*)(ws + 167772160ull);       // 4M bf16   = 8,388,608 B
  bf16_t* w2b       = (bf16_t*)(ws + 176160768ull);       // 4M bf16   = 8,388,608 B
  float*  chunk_end = (float*)(ws + 184549376ull);        // 128K f32  = 524,288 B
  float*  carry_in  = (float*)(ws + 185073664ull);        // 128K f32  = 524,288 B
  float*  loss_acc  = (float*)(ws + 185597952ull);        // 4 B

  hipMemsetAsync(loss_acc, 0, sizeof(float), stream);

  // weights -> bf16 (4,194,304 elems each; 4/thread)
  cvt_bf16_kernel<<<4096, 256, 0, stream>>>(w1, w1b);
  cvt_bf16_kernel<<<4096, 256, 0, stream>>>(w2, w2b);

  // chunked EMA scan -> prev states (bf16) + final_state (fp32, d_out tail)
  scan_chunk_kernel<<<(BSZ * NCHUNK * DIM) / 256, 256, 0, stream>>>(x, chunk_end);
  scan_carry_kernel<<<(BSZ * DIM) / 256, 256, 0, stream>>>(chunk_end, carry_in,
                                                           out + 16777217);
  scan_emit_kernel<<<(BSZ * NCHUNK * DIM) / 256, 256, 0, stream>>>(x, carry_in, prev);

  // h = silu(prev @ w1^T)  : [16384 x 1024] x [4096 x 1024]^T -> bf16 [16384 x 4096]
  gemm256_kernel<MDIM, DIM, BT / 256, 0>
      <<<(BT / 256) * (MDIM / 256), 512, 0, stream>>>(prev, w1b, h, nullptr, nullptr);

  // mem_out = h @ w2^T : [16384 x 4096] x [1024 x 4096]^T -> fp32 [16384 x 1024]
  // fused: loss partial sums vs x
  gemm256_kernel<DIM, MDIM, BT / 256, 1>
      <<<(BT / 256) * (DIM / 256), 512, 0, stream>>>(h, w2b, out, x, loss_acc);

  finalize_loss_kernel<<<1, 64, 0, stream>>>(loss_acc, out + 16777216);
}